// Round 5
// baseline (99.345 us; speedup 1.0000x reference)
//
#include <hip/hip_runtime.h>

// YOLO loss on MI355X. Inputs: yhat (N,52,52,255) f32, y (N,52,52,255) f32,
// anchors (3,3,2) f32, epoch (ignored: epoch=1 >= EPOCH_PRIOR=0 -> prior=0).
// Outputs: concat [coord(N), class(N), noobj(N), obj(N), prior(1)] f32.
//
// R4: R3's persistent-block single-phase structure, plus:
//  - BIMG 16->32 (grid 2048 = 8 blocks/CU target): occupancy was grid-capped.
//  - Vectorized loads: box xywh as one align(4) float4 (+ scalar conf), and
//    classes re-partitioned so lane `sub` owns contiguous classes
//    [5*sub, 5*sub+4] -> float4 + scalar. VMEM instrs/iteration: 60 -> 24.

constexpr int SD      = 52;
constexpr int S2CELLS = SD * SD;        // 2704
constexpr int CH      = 255;            // (5+80)*3
constexpr int CPB     = 16;             // cells per chunk (4 waves x 4 groups)
constexpr int BIMG    = 32;             // blocks per image
constexpr int CHUNKS  = S2CELLS / CPB;  // 169
constexpr float EPSF  = 1e-6f;

// float4 with alignment 4 (cell base = cellImg*255 floats -> arbitrary mod 16B;
// gfx950 multi-dword global loads only need dword alignment)
typedef float f4u __attribute__((ext_vector_type(4), aligned(4)));

__device__ __forceinline__ float flog(float x) {
    return __builtin_amdgcn_logf(x) * 0.69314718055994531f;  // v_log_f32 * ln2
}
__device__ __forceinline__ float frcp(float x) {
    return __builtin_amdgcn_rcpf(x);
}
__device__ __forceinline__ float sel3(int s, float a, float b, float c) {
    return (s == 0) ? a : ((s == 1) ? b : c);   // 2x v_cndmask
}

__global__ __launch_bounds__(256, 4) void yolo_loss_kernel(
    const float* __restrict__ yhat, const float* __restrict__ yt,
    const float* __restrict__ anchors, float* __restrict__ out, int N)
{
    __shared__ float red[4][4];

    const int tid  = threadIdx.x;
    const int wv   = tid >> 6;
    const int lane = tid & 63;
    const int grp  = lane >> 4;
    const int sub  = lane & 15;
    const int cellLocal = wv * 4 + grp;

    const int n   = blockIdx.x >> 5;          // image index (BIMG = 32)
    const int blk = blockIdx.x & (BIMG - 1);  // block within image

    // anchors[scale_idx=2][b][wh] -> flat offset 12 + 2b
    const float aw0 = anchors[12], ah0 = anchors[13];
    const float aw1 = anchors[14], ah1 = anchors[15];
    const float aw2 = anchors[16], ah2 = anchors[17];
    const float rw0 = frcp(aw0), rh0 = frcp(ah0);
    const float rw1 = frcp(aw1), rh1 = frcp(ah1);
    const float rw2 = frcp(aw2), rh2 = frcp(ah2);
    const float invS = 1.0f / (float)SD;

    float acc_coord = 0.f, acc_class = 0.f, acc_noobj = 0.f, acc_obj = 0.f;

    const size_t imgBase = (size_t)n * S2CELLS * CH;
    const int clsOff = 5 + 5 * sub;   // lane's contiguous class window

    for (int c = blk; c < CHUNKS; c += BIMG) {
        const int cellImg = c * CPB + cellLocal;
        const float* __restrict__ A = yhat + imgBase + (size_t)cellImg * CH;
        const float* __restrict__ T = yt   + imgBase + (size_t)cellImg * CH;

        // ---- ALL loads first (addresses independent of compute) ----
        f4u  abox[3], tbox[3];          // x,y,w,h (group-broadcast)
        float acf[3], tcf[3];           // conf
        f4u  acl4[3], tcl4[3];          // classes 5*sub .. 5*sub+3
        float acl1[3], tcl1[3];         // class 5*sub+4
#pragma unroll
        for (int b = 0; b < 3; b++) {
            abox[b] = *reinterpret_cast<const f4u*>(A + b * 85);
            tbox[b] = *reinterpret_cast<const f4u*>(T + b * 85);
            acf[b]  = A[b * 85 + 4];
            tcf[b]  = T[b * 85 + 4];
            acl4[b] = *reinterpret_cast<const f4u*>(A + b * 85 + clsOff);
            tcl4[b] = *reinterpret_cast<const f4u*>(T + b * 85 + clsOff);
            acl1[b] = A[b * 85 + clsOff + 4];
            tcl1[b] = T[b * 85 + clsOff + 4];
        }

        const int irow = cellImg / SD;
        const int jcol = cellImg - irow * SD;
        const float jf = (float)jcol, if_ = (float)irow;

        // ---- box geometry ----
        float hx1[3], hx2[3], hy1[3], hy2[3], ha[3];
        float tx1[3], tx2[3], ty1[3], ty2[3], ta[3];
#pragma unroll
        for (int b = 0; b < 3; b++) {
            float w = abox[b].z, h = abox[b].w;
            float cx = (abox[b].x + jf) * invS, cy = (abox[b].y + if_) * invS;
            hx1[b] = cx - 0.5f * w; hx2[b] = cx + 0.5f * w;
            hy1[b] = cy - 0.5f * h; hy2[b] = cy + 0.5f * h;
            ha[b]  = (hx2[b] - hx1[b]) * (hy2[b] - hy1[b]);
        }
#pragma unroll
        for (int b = 0; b < 3; b++) {
            float w = tbox[b].z, h = tbox[b].w;
            float cx = (tbox[b].x + jf) * invS, cy = (tbox[b].y + if_) * invS;
            tx1[b] = cx - 0.5f * w; tx2[b] = cx + 0.5f * w;
            ty1[b] = cy - 0.5f * h; ty2[b] = cy + 0.5f * h;
            ta[b]  = (tx2[b] - tx1[b]) * (ty2[b] - ty1[b]);
        }

        float iou[3][3];
#pragma unroll
        for (int bp = 0; bp < 3; bp++)
#pragma unroll
            for (int bt = 0; bt < 3; bt++) {
                float wi = fminf(hx2[bp], tx2[bt]) - fmaxf(hx1[bp], tx1[bt]);
                wi = fmaxf(wi, 0.0f);
                float hi = fminf(hy2[bp], ty2[bt]) - fmaxf(hy1[bp], ty1[bt]);
                hi = fmaxf(hi, 0.0f);
                float inter = wi * hi;
                float uni   = ha[bp] + ta[bt] - inter;
                iou[bp][bt] = inter * frcp(uni + EPSF);
            }

        // no-obj (target 0, NO_OBJ_V3)
#pragma unroll
        for (int bp = 0; bp < 3; bp++) {
            float m = fmaxf(fmaxf(iou[bp][0], iou[bp][1]), iou[bp][2]);
            acc_noobj += (m < 0.7f) ? acf[bp] * acf[bp] : 0.0f;
        }

        // argmax over pred boxes per target (first-max ties, like jnp.argmax)
        int sel[3];
#pragma unroll
        for (int bt = 0; bt < 3; bt++) {
            int s = 0; float v = iou[0][bt];
            if (iou[1][bt] > v) { v = iou[1][bt]; s = 1; }
            if (iou[2][bt] > v) { s = 2; }
            sel[bt] = s;
        }

        float ho[3];
#pragma unroll
        for (int bt = 0; bt < 3; bt++) {
            int sp = sel[bt];
            float hoo = (tcf[bt] > 0.0f) ? 1.0f : 0.0f;
            ho[bt] = hoo;
            float phx = sel3(sp, abox[0].x, abox[1].x, abox[2].x);
            float phy = sel3(sp, abox[0].y, abox[1].y, abox[2].y);
            float phw = sel3(sp, abox[0].z, abox[1].z, abox[2].z);
            float phh = sel3(sp, abox[0].w, abox[1].w, abox[2].w);
            float phc = sel3(sp, acf[0],  acf[1],  acf[2]);
            float rwp = sel3(sp, rw0, rw1, rw2);
            float rhp = sel3(sp, rh0, rh1, rh2);
            float rwt = (bt == 0) ? rw0 : ((bt == 1) ? rw1 : rw2);
            float rht = (bt == 0) ? rh0 : ((bt == 1) ? rh1 : rh2);
            float dx  = phx - tbox[bt].x;
            float dy  = phy - tbox[bt].y;
            float dlw = flog(phw * rwp + EPSF) - flog(tbox[bt].z * rwt + EPSF);
            float dlh = flog(phh * rhp + EPSF) - flog(tbox[bt].w * rht + EPSF);
            float csum = dx * dx + dy * dy + dlw * dlw + dlh * dlh;
            acc_coord += csum * hoo * (2.0f - tbox[bt].z * tbox[bt].w);
            float dcf = phc - tcf[bt];
            acc_obj += dcf * dcf * hoo;
        }

        // class: select VALUES (cndmask), not addresses
#pragma unroll
        for (int bt = 0; bt < 3; bt++) {
            int sp = sel[bt];
            float s = 0.0f;
#pragma unroll
            for (int k = 0; k < 4; k++) {
                float pa = sel3(sp, acl4[0][k], acl4[1][k], acl4[2][k]);
                float d  = pa - tcl4[bt][k];
                s += d * d;
            }
            {
                float pa = sel3(sp, acl1[0], acl1[1], acl1[2]);
                float d  = pa - tcl1[bt];
                s += d * d;
            }
            acc_class += s * ho[bt];
        }
    }

    // ---- single final reduction ----
    // coord/noobj/obj replicated x16 within each group -> scale by 1/16 exact.
#pragma unroll
    for (int off = 1; off < 64; off <<= 1) {
        acc_coord += __shfl_xor(acc_coord, off, 64);
        acc_class += __shfl_xor(acc_class, off, 64);
        acc_noobj += __shfl_xor(acc_noobj, off, 64);
        acc_obj   += __shfl_xor(acc_obj,   off, 64);
    }
    if (lane == 0) {
        red[wv][0] = acc_coord; red[wv][1] = acc_class;
        red[wv][2] = acc_noobj; red[wv][3] = acc_obj;
    }
    __syncthreads();
    if (tid < 4) {
        float s = red[0][tid] + red[1][tid] + red[2][tid] + red[3][tid];
        if (tid != 1) s *= 0.0625f;   // un-replicate coord/noobj/obj
        atomicAdd(&out[tid * N + n], s);
    }
}

extern "C" void kernel_launch(void* const* d_in, const int* in_sizes, int n_in,
                              void* d_out, int out_size, void* d_ws, size_t ws_size,
                              hipStream_t stream) {
    const float* yhat = (const float*)d_in[0];
    const float* yv   = (const float*)d_in[1];
    const float* anc  = (const float*)d_in[2];
    float* out = (float*)d_out;

    const int N = in_sizes[0] / (S2CELLS * CH);

    hipMemsetAsync(d_out, 0, (size_t)out_size * sizeof(float), stream);

    dim3 grid(N * BIMG);
    yolo_loss_kernel<<<grid, 256, 0, stream>>>(yhat, yv, anc, out, N);
}

// Round 6
// 80.184 us; speedup vs baseline: 1.2390x; 1.2390x over previous
//
#include <hip/hip_runtime.h>

// YOLO loss on MI355X. Inputs: yhat (N,52,52,255) f32, y (N,52,52,255) f32,
// anchors (3,3,2) f32, epoch (ignored: epoch=1 >= EPOCH_PRIOR=0 -> prior=0).
// Outputs: concat [coord(N), class(N), noobj(N), obj(N), prior(1)] f32.
//
// R5 = R3 (known-good 78.5us: persistent blocks, scalar single-phase loads,
// 60 VGPR no spill) with exactly ONE change: BIMG 16->32 (grid 2048 =
// 8 blocks/CU) to lift the grid-imposed occupancy cap. R4's float4
// vectorization caused scratch spills (WRITE_SIZE 128KB->22.8MB) - reverted.

constexpr int SD      = 52;
constexpr int S2CELLS = SD * SD;        // 2704
constexpr int CH      = 255;            // (5+80)*3
constexpr int CPB     = 16;             // cells per chunk (4 waves x 4 groups)
constexpr int BIMG    = 32;             // blocks per image (R3: 16)
constexpr int CHUNKS  = S2CELLS / CPB;  // 169
constexpr float EPSF  = 1e-6f;

__device__ __forceinline__ float flog(float x) {
    return __builtin_amdgcn_logf(x) * 0.69314718055994531f;  // v_log_f32 * ln2
}
__device__ __forceinline__ float frcp(float x) {
    return __builtin_amdgcn_rcpf(x);
}
__device__ __forceinline__ float sel3(int s, float a, float b, float c) {
    return (s == 0) ? a : ((s == 1) ? b : c);   // 2x v_cndmask
}

__global__ __launch_bounds__(256, 4) void yolo_loss_kernel(
    const float* __restrict__ yhat, const float* __restrict__ yt,
    const float* __restrict__ anchors, float* __restrict__ out, int N)
{
    __shared__ float red[4][4];

    const int tid  = threadIdx.x;
    const int wv   = tid >> 6;
    const int lane = tid & 63;
    const int grp  = lane >> 4;
    const int sub  = lane & 15;
    const int cellLocal = wv * 4 + grp;

    const int n   = blockIdx.x >> 5;          // image index (BIMG = 32)
    const int blk = blockIdx.x & (BIMG - 1);  // block within image

    // anchors[scale_idx=2][b][wh] -> flat offset 12 + 2b
    const float aw0 = anchors[12], ah0 = anchors[13];
    const float aw1 = anchors[14], ah1 = anchors[15];
    const float aw2 = anchors[16], ah2 = anchors[17];
    const float rw0 = frcp(aw0), rh0 = frcp(ah0);
    const float rw1 = frcp(aw1), rh1 = frcp(ah1);
    const float rw2 = frcp(aw2), rh2 = frcp(ah2);
    const float invS = 1.0f / (float)SD;

    float acc_coord = 0.f, acc_class = 0.f, acc_noobj = 0.f, acc_obj = 0.f;

    const size_t imgBase = (size_t)n * S2CELLS * CH;

    for (int c = blk; c < CHUNKS; c += BIMG) {
        const int cellImg = c * CPB + cellLocal;
        const float* __restrict__ A = yhat + imgBase + (size_t)cellImg * CH;
        const float* __restrict__ T = yt   + imgBase + (size_t)cellImg * CH;

        // ---- ALL loads first (addresses independent of any compute) ----
        float av[3][5], tv[3][5];     // box: x,y,w,h,conf (group-broadcast)
        float acv[3][5], tcv[3][5];   // class: lane sub covers c = sub+16k
#pragma unroll
        for (int b = 0; b < 3; b++)
#pragma unroll
            for (int k = 0; k < 5; k++) {
                av[b][k] = A[b * 85 + k];
                tv[b][k] = T[b * 85 + k];
            }
#pragma unroll
        for (int b = 0; b < 3; b++)
#pragma unroll
            for (int k = 0; k < 5; k++) {
                int cc = b * 85 + 5 + sub + k * 16;
                acv[b][k] = A[cc];
                tcv[b][k] = T[cc];
            }

        const int irow = cellImg / SD;
        const int jcol = cellImg - irow * SD;
        const float jf = (float)jcol, if_ = (float)irow;

        // ---- box geometry ----
        float hx1[3], hx2[3], hy1[3], hy2[3], ha[3];
        float tx1[3], tx2[3], ty1[3], ty2[3], ta[3];
#pragma unroll
        for (int b = 0; b < 3; b++) {
            float w = av[b][2], h = av[b][3];
            float cx = (av[b][0] + jf) * invS, cy = (av[b][1] + if_) * invS;
            hx1[b] = cx - 0.5f * w; hx2[b] = cx + 0.5f * w;
            hy1[b] = cy - 0.5f * h; hy2[b] = cy + 0.5f * h;
            ha[b]  = (hx2[b] - hx1[b]) * (hy2[b] - hy1[b]);
        }
#pragma unroll
        for (int b = 0; b < 3; b++) {
            float w = tv[b][2], h = tv[b][3];
            float cx = (tv[b][0] + jf) * invS, cy = (tv[b][1] + if_) * invS;
            tx1[b] = cx - 0.5f * w; tx2[b] = cx + 0.5f * w;
            ty1[b] = cy - 0.5f * h; ty2[b] = cy + 0.5f * h;
            ta[b]  = (tx2[b] - tx1[b]) * (ty2[b] - ty1[b]);
        }

        float iou[3][3];
#pragma unroll
        for (int bp = 0; bp < 3; bp++)
#pragma unroll
            for (int bt = 0; bt < 3; bt++) {
                float wi = fminf(hx2[bp], tx2[bt]) - fmaxf(hx1[bp], tx1[bt]);
                wi = fmaxf(wi, 0.0f);
                float hi = fminf(hy2[bp], ty2[bt]) - fmaxf(hy1[bp], ty1[bt]);
                hi = fmaxf(hi, 0.0f);
                float inter = wi * hi;
                float uni   = ha[bp] + ta[bt] - inter;
                iou[bp][bt] = inter * frcp(uni + EPSF);
            }

        // no-obj (target 0, NO_OBJ_V3)
#pragma unroll
        for (int bp = 0; bp < 3; bp++) {
            float m = fmaxf(fmaxf(iou[bp][0], iou[bp][1]), iou[bp][2]);
            acc_noobj += (m < 0.7f) ? av[bp][4] * av[bp][4] : 0.0f;
        }

        // argmax over pred boxes per target (first-max ties, like jnp.argmax)
        int sel[3];
#pragma unroll
        for (int bt = 0; bt < 3; bt++) {
            int s = 0; float v = iou[0][bt];
            if (iou[1][bt] > v) { v = iou[1][bt]; s = 1; }
            if (iou[2][bt] > v) { s = 2; }
            sel[bt] = s;
        }

        float ho[3];
#pragma unroll
        for (int bt = 0; bt < 3; bt++) {
            int sp = sel[bt];
            float hoo = (tv[bt][4] > 0.0f) ? 1.0f : 0.0f;
            ho[bt] = hoo;
            float phx = sel3(sp, av[0][0], av[1][0], av[2][0]);
            float phy = sel3(sp, av[0][1], av[1][1], av[2][1]);
            float phw = sel3(sp, av[0][2], av[1][2], av[2][2]);
            float phh = sel3(sp, av[0][3], av[1][3], av[2][3]);
            float phc = sel3(sp, av[0][4], av[1][4], av[2][4]);
            float rwp = sel3(sp, rw0, rw1, rw2);
            float rhp = sel3(sp, rh0, rh1, rh2);
            float rwt = (bt == 0) ? rw0 : ((bt == 1) ? rw1 : rw2);
            float rht = (bt == 0) ? rh0 : ((bt == 1) ? rh1 : rh2);
            float dx  = phx - tv[bt][0];
            float dy  = phy - tv[bt][1];
            float dlw = flog(phw * rwp + EPSF) - flog(tv[bt][2] * rwt + EPSF);
            float dlh = flog(phh * rhp + EPSF) - flog(tv[bt][3] * rht + EPSF);
            float csum = dx * dx + dy * dy + dlw * dlw + dlh * dlh;
            acc_coord += csum * hoo * (2.0f - tv[bt][2] * tv[bt][3]);
            float dcf = phc - tv[bt][4];
            acc_obj += dcf * dcf * hoo;
        }

        // class: select VALUES (cndmask), not addresses
#pragma unroll
        for (int bt = 0; bt < 3; bt++) {
            int sp = sel[bt];
            float s = 0.0f;
#pragma unroll
            for (int k = 0; k < 5; k++) {
                float pa = sel3(sp, acv[0][k], acv[1][k], acv[2][k]);
                float d  = pa - tcv[bt][k];
                s += d * d;
            }
            acc_class += s * ho[bt];
        }
    }

    // ---- single final reduction ----
    // coord/noobj/obj replicated x16 within each group -> scale by 1/16 exact.
#pragma unroll
    for (int off = 1; off < 64; off <<= 1) {
        acc_coord += __shfl_xor(acc_coord, off, 64);
        acc_class += __shfl_xor(acc_class, off, 64);
        acc_noobj += __shfl_xor(acc_noobj, off, 64);
        acc_obj   += __shfl_xor(acc_obj,   off, 64);
    }
    if (lane == 0) {
        red[wv][0] = acc_coord; red[wv][1] = acc_class;
        red[wv][2] = acc_noobj; red[wv][3] = acc_obj;
    }
    __syncthreads();
    if (tid < 4) {
        float s = red[0][tid] + red[1][tid] + red[2][tid] + red[3][tid];
        if (tid != 1) s *= 0.0625f;   // un-replicate coord/noobj/obj
        atomicAdd(&out[tid * N + n], s);
    }
}

extern "C" void kernel_launch(void* const* d_in, const int* in_sizes, int n_in,
                              void* d_out, int out_size, void* d_ws, size_t ws_size,
                              hipStream_t stream) {
    const float* yhat = (const float*)d_in[0];
    const float* yv   = (const float*)d_in[1];
    const float* anc  = (const float*)d_in[2];
    float* out = (float*)d_out;

    const int N = in_sizes[0] / (S2CELLS * CH);

    hipMemsetAsync(d_out, 0, (size_t)out_size * sizeof(float), stream);

    dim3 grid(N * BIMG);
    yolo_loss_kernel<<<grid, 256, 0, stream>>>(yhat, yv, anc, out, N);
}

// Round 7
// 79.032 us; speedup vs baseline: 1.2570x; 1.0146x over previous
//
#include <hip/hip_runtime.h>

// YOLO loss on MI355X. Inputs: yhat (N,52,52,255) f32, y (N,52,52,255) f32,
// anchors (3,3,2) f32, epoch (ignored: epoch=1 >= EPOCH_PRIOR=0 -> prior=0).
// Outputs: concat [coord(N), class(N), noobj(N), obj(N), prior(1)] f32.
//
// R6 = R5's persistent-block structure, with the 60 scalar global loads per
// iteration replaced by 8 float4 global loads + wave-PRIVATE LDS staging
// (no __syncthreads: each wave stages and reads only its own slab; the 4
// cells a wave owns are contiguous in memory, 2x1020 floats, 16B-aligned).
// Box/class values are then read from LDS (broadcast reads bank-free).

constexpr int SD      = 52;
constexpr int S2CELLS = SD * SD;        // 2704
constexpr int CH      = 255;            // (5+80)*3
constexpr int CPB     = 16;             // cells per chunk (4 waves x 4 cells)
constexpr int BIMG    = 32;             // blocks per image
constexpr int CHUNKS  = S2CELLS / CPB;  // 169
constexpr float EPSF  = 1e-6f;

__device__ __forceinline__ float flog(float x) {
    return __builtin_amdgcn_logf(x) * 0.69314718055994531f;  // v_log_f32 * ln2
}
__device__ __forceinline__ float frcp(float x) {
    return __builtin_amdgcn_rcpf(x);
}
__device__ __forceinline__ float sel3(int s, float a, float b, float c) {
    return (s == 0) ? a : ((s == 1) ? b : c);   // 2x v_cndmask
}

__global__ __launch_bounds__(256, 4) void yolo_loss_kernel(
    const float* __restrict__ yhat, const float* __restrict__ yt,
    const float* __restrict__ anchors, float* __restrict__ out, int N)
{
    // per-wave private slabs: [wave][tensor][4 cells x 255 floats]
    __shared__ __align__(16) float slab[4][2][4 * CH];   // 32640 B
    __shared__ float red[4][4];

    const int tid  = threadIdx.x;
    const int wv   = tid >> 6;
    const int lane = tid & 63;
    const int grp  = lane >> 4;
    const int sub  = lane & 15;

    const int n   = blockIdx.x >> 5;          // image index (BIMG = 32)
    const int blk = blockIdx.x & (BIMG - 1);  // block within image

    // anchors[scale_idx=2][b][wh] -> flat offset 12 + 2b
    const float aw0 = anchors[12], ah0 = anchors[13];
    const float aw1 = anchors[14], ah1 = anchors[15];
    const float aw2 = anchors[16], ah2 = anchors[17];
    const float rw0 = frcp(aw0), rh0 = frcp(ah0);
    const float rw1 = frcp(aw1), rh1 = frcp(ah1);
    const float rw2 = frcp(aw2), rh2 = frcp(ah2);
    const float invS = 1.0f / (float)SD;

    float acc_coord = 0.f, acc_class = 0.f, acc_noobj = 0.f, acc_obj = 0.f;

    const size_t imgBase = (size_t)n * S2CELLS * CH;

    for (int c = blk; c < CHUNKS; c += BIMG) {
        // ---- stage this wave's 4 contiguous cells of both tensors ----
        const int cellImg0 = c * CPB + wv * 4;             // wave's first cell
        const float4* __restrict__ gA =
            (const float4*)(yhat + imgBase + (size_t)cellImg0 * CH); // 16B aligned
        const float4* __restrict__ gT =
            (const float4*)(yt   + imgBase + (size_t)cellImg0 * CH);
        float4* sA4 = (float4*)&slab[wv][0][0];
        float4* sT4 = (float4*)&slab[wv][1][0];
#pragma unroll
        for (int r = 0; r < 4; r++) {
            int i = lane + r * 64;
            if (i < 255) {             // 255 float4 per tensor per wave
                sA4[i] = gA[i];
                sT4[i] = gT[i];
            }
        }
        // wave-private: no barrier; compiler inserts vmcnt/lgkmcnt ordering

        const int cellImg = cellImg0 + grp;
        const float* A = &slab[wv][0][grp * CH];
        const float* T = &slab[wv][1][grp * CH];

        // ---- per-cell values from LDS ----
        float av[3][5], tv[3][5];     // box: x,y,w,h,conf (broadcast reads)
        float acv[3][5], tcv[3][5];   // class: lane sub covers cc = sub+16k
#pragma unroll
        for (int b = 0; b < 3; b++)
#pragma unroll
            for (int k = 0; k < 5; k++) {
                av[b][k] = A[b * 85 + k];
                tv[b][k] = T[b * 85 + k];
            }
#pragma unroll
        for (int b = 0; b < 3; b++)
#pragma unroll
            for (int k = 0; k < 5; k++) {
                int cc = b * 85 + 5 + sub + k * 16;
                acv[b][k] = A[cc];
                tcv[b][k] = T[cc];
            }

        const int irow = cellImg / SD;
        const int jcol = cellImg - irow * SD;
        const float jf = (float)jcol, if_ = (float)irow;

        // ---- box geometry ----
        float hx1[3], hx2[3], hy1[3], hy2[3], ha[3];
        float tx1[3], tx2[3], ty1[3], ty2[3], ta[3];
#pragma unroll
        for (int b = 0; b < 3; b++) {
            float w = av[b][2], h = av[b][3];
            float cx = (av[b][0] + jf) * invS, cy = (av[b][1] + if_) * invS;
            hx1[b] = cx - 0.5f * w; hx2[b] = cx + 0.5f * w;
            hy1[b] = cy - 0.5f * h; hy2[b] = cy + 0.5f * h;
            ha[b]  = (hx2[b] - hx1[b]) * (hy2[b] - hy1[b]);
        }
#pragma unroll
        for (int b = 0; b < 3; b++) {
            float w = tv[b][2], h = tv[b][3];
            float cx = (tv[b][0] + jf) * invS, cy = (tv[b][1] + if_) * invS;
            tx1[b] = cx - 0.5f * w; tx2[b] = cx + 0.5f * w;
            ty1[b] = cy - 0.5f * h; ty2[b] = cy + 0.5f * h;
            ta[b]  = (tx2[b] - tx1[b]) * (ty2[b] - ty1[b]);
        }

        float iou[3][3];
#pragma unroll
        for (int bp = 0; bp < 3; bp++)
#pragma unroll
            for (int bt = 0; bt < 3; bt++) {
                float wi = fminf(hx2[bp], tx2[bt]) - fmaxf(hx1[bp], tx1[bt]);
                wi = fmaxf(wi, 0.0f);
                float hi = fminf(hy2[bp], ty2[bt]) - fmaxf(hy1[bp], ty1[bt]);
                hi = fmaxf(hi, 0.0f);
                float inter = wi * hi;
                float uni   = ha[bp] + ta[bt] - inter;
                iou[bp][bt] = inter * frcp(uni + EPSF);
            }

        // no-obj (target 0, NO_OBJ_V3)
#pragma unroll
        for (int bp = 0; bp < 3; bp++) {
            float m = fmaxf(fmaxf(iou[bp][0], iou[bp][1]), iou[bp][2]);
            acc_noobj += (m < 0.7f) ? av[bp][4] * av[bp][4] : 0.0f;
        }

        // argmax over pred boxes per target (first-max ties, like jnp.argmax)
        int sel[3];
#pragma unroll
        for (int bt = 0; bt < 3; bt++) {
            int s = 0; float v = iou[0][bt];
            if (iou[1][bt] > v) { v = iou[1][bt]; s = 1; }
            if (iou[2][bt] > v) { s = 2; }
            sel[bt] = s;
        }

        float ho[3];
#pragma unroll
        for (int bt = 0; bt < 3; bt++) {
            int sp = sel[bt];
            float hoo = (tv[bt][4] > 0.0f) ? 1.0f : 0.0f;
            ho[bt] = hoo;
            float phx = sel3(sp, av[0][0], av[1][0], av[2][0]);
            float phy = sel3(sp, av[0][1], av[1][1], av[2][1]);
            float phw = sel3(sp, av[0][2], av[1][2], av[2][2]);
            float phh = sel3(sp, av[0][3], av[1][3], av[2][3]);
            float phc = sel3(sp, av[0][4], av[1][4], av[2][4]);
            float rwp = sel3(sp, rw0, rw1, rw2);
            float rhp = sel3(sp, rh0, rh1, rh2);
            float rwt = (bt == 0) ? rw0 : ((bt == 1) ? rw1 : rw2);
            float rht = (bt == 0) ? rh0 : ((bt == 1) ? rh1 : rh2);
            float dx  = phx - tv[bt][0];
            float dy  = phy - tv[bt][1];
            float dlw = flog(phw * rwp + EPSF) - flog(tv[bt][2] * rwt + EPSF);
            float dlh = flog(phh * rhp + EPSF) - flog(tv[bt][3] * rht + EPSF);
            float csum = dx * dx + dy * dy + dlw * dlw + dlh * dlh;
            acc_coord += csum * hoo * (2.0f - tv[bt][2] * tv[bt][3]);
            float dcf = phc - tv[bt][4];
            acc_obj += dcf * dcf * hoo;
        }

        // class: select VALUES (cndmask), not addresses
#pragma unroll
        for (int bt = 0; bt < 3; bt++) {
            int sp = sel[bt];
            float s = 0.0f;
#pragma unroll
            for (int k = 0; k < 5; k++) {
                float pa = sel3(sp, acv[0][k], acv[1][k], acv[2][k]);
                float d  = pa - tcv[bt][k];
                s += d * d;
            }
            acc_class += s * ho[bt];
        }
    }

    // ---- single final reduction ----
    // coord/noobj/obj replicated x16 within each group -> scale by 1/16 exact.
#pragma unroll
    for (int off = 1; off < 64; off <<= 1) {
        acc_coord += __shfl_xor(acc_coord, off, 64);
        acc_class += __shfl_xor(acc_class, off, 64);
        acc_noobj += __shfl_xor(acc_noobj, off, 64);
        acc_obj   += __shfl_xor(acc_obj,   off, 64);
    }
    if (lane == 0) {
        red[wv][0] = acc_coord; red[wv][1] = acc_class;
        red[wv][2] = acc_noobj; red[wv][3] = acc_obj;
    }
    __syncthreads();
    if (tid < 4) {
        float s = red[0][tid] + red[1][tid] + red[2][tid] + red[3][tid];
        if (tid != 1) s *= 0.0625f;   // un-replicate coord/noobj/obj
        atomicAdd(&out[tid * N + n], s);
    }
}

extern "C" void kernel_launch(void* const* d_in, const int* in_sizes, int n_in,
                              void* d_out, int out_size, void* d_ws, size_t ws_size,
                              hipStream_t stream) {
    const float* yhat = (const float*)d_in[0];
    const float* yv   = (const float*)d_in[1];
    const float* anc  = (const float*)d_in[2];
    float* out = (float*)d_out;

    const int N = in_sizes[0] / (S2CELLS * CH);

    hipMemsetAsync(d_out, 0, (size_t)out_size * sizeof(float), stream);

    dim3 grid(N * BIMG);
    yolo_loss_kernel<<<grid, 256, 0, stream>>>(yhat, yv, anc, out, N);
}

// Round 8
// 78.564 us; speedup vs baseline: 1.2645x; 1.0060x over previous
//
#include <hip/hip_runtime.h>

// YOLO loss on MI355X. Inputs: yhat (N,52,52,255) f32, y (N,52,52,255) f32,
// anchors (3,3,2) f32, epoch (ignored: epoch=1 >= EPOCH_PRIOR=0 -> prior=0).
// Outputs: concat [coord(N), class(N), noobj(N), obj(N), prior(1)] f32.
//
// R7: latency-bound fix. Evidence: L3-warm replays (23MB fetch) run exactly as
// slow as HBM-heavy ones -> exposed load latency, not bandwidth. Structure:
// one wave per block (64 thr), 32 waves/image, all 2048 waves resident and
// persistent (21-22 iters). 2-stage register pipeline: issue chunk c+1's 24
// vectorized loads BEFORE computing chunk c. launch_bounds(64,2) -> 256 VGPR
// cap so the two in-flight chunk register sets don't spill (R4's failure).

constexpr int SD      = 52;
constexpr int S2CELLS = SD * SD;     // 2704
constexpr int CH      = 255;         // (5+80)*3
constexpr int W       = 32;          // waves (blocks) per image
constexpr int NCH     = S2CELLS / 4; // 676 chunks of 4 cells
constexpr float EPSF  = 1e-6f;

// float4 with alignment 4 (cell base = cellImg*255 floats -> 16B-unaligned;
// verified correct in R4: gfx950 multi-dword loads need only dword alignment)
typedef float f4u __attribute__((ext_vector_type(4), aligned(4)));

__device__ __forceinline__ float flog(float x) {
    return __builtin_amdgcn_logf(x) * 0.69314718055994531f;  // v_log_f32 * ln2
}
__device__ __forceinline__ float frcp(float x) {
    return __builtin_amdgcn_rcpf(x);
}
__device__ __forceinline__ float sel3(int s, float a, float b, float c) {
    return (s == 0) ? a : ((s == 1) ? b : c);   // 2x v_cndmask
}

struct Chunk {
    f4u  abox[3], tbox[3];   // x,y,w,h per box (group-broadcast)
    f4u  acl4[3], tcl4[3];   // classes 5*sub .. 5*sub+3
    float acf[3], tcf[3];    // conf
    float acl1[3], tcl1[3];  // class 5*sub+4
};

__device__ __forceinline__ void loadChunk(Chunk& K,
    const float* __restrict__ A, const float* __restrict__ T, int clsOff)
{
#pragma unroll
    for (int b = 0; b < 3; b++) {
        K.abox[b] = *reinterpret_cast<const f4u*>(A + b * 85);
        K.tbox[b] = *reinterpret_cast<const f4u*>(T + b * 85);
        K.acf[b]  = A[b * 85 + 4];
        K.tcf[b]  = T[b * 85 + 4];
        K.acl4[b] = *reinterpret_cast<const f4u*>(A + b * 85 + clsOff);
        K.tcl4[b] = *reinterpret_cast<const f4u*>(T + b * 85 + clsOff);
        K.acl1[b] = A[b * 85 + clsOff + 4];
        K.tcl1[b] = T[b * 85 + clsOff + 4];
    }
}

__device__ __forceinline__ void computeChunk(const Chunk& K, int cellImg,
    float rw0, float rh0, float rw1, float rh1, float rw2, float rh2,
    float& acc_coord, float& acc_class, float& acc_noobj, float& acc_obj)
{
    const float invS = 1.0f / (float)SD;
    const int irow = cellImg / SD;
    const int jcol = cellImg - irow * SD;
    const float jf = (float)jcol, if_ = (float)irow;

    float hx1[3], hx2[3], hy1[3], hy2[3], ha[3];
    float tx1[3], tx2[3], ty1[3], ty2[3], ta[3];
#pragma unroll
    for (int b = 0; b < 3; b++) {
        float w = K.abox[b].z, h = K.abox[b].w;
        float cx = (K.abox[b].x + jf) * invS, cy = (K.abox[b].y + if_) * invS;
        hx1[b] = cx - 0.5f * w; hx2[b] = cx + 0.5f * w;
        hy1[b] = cy - 0.5f * h; hy2[b] = cy + 0.5f * h;
        ha[b]  = (hx2[b] - hx1[b]) * (hy2[b] - hy1[b]);
    }
#pragma unroll
    for (int b = 0; b < 3; b++) {
        float w = K.tbox[b].z, h = K.tbox[b].w;
        float cx = (K.tbox[b].x + jf) * invS, cy = (K.tbox[b].y + if_) * invS;
        tx1[b] = cx - 0.5f * w; tx2[b] = cx + 0.5f * w;
        ty1[b] = cy - 0.5f * h; ty2[b] = cy + 0.5f * h;
        ta[b]  = (tx2[b] - tx1[b]) * (ty2[b] - ty1[b]);
    }

    float iou[3][3];
#pragma unroll
    for (int bp = 0; bp < 3; bp++)
#pragma unroll
        for (int bt = 0; bt < 3; bt++) {
            float wi = fminf(hx2[bp], tx2[bt]) - fmaxf(hx1[bp], tx1[bt]);
            wi = fmaxf(wi, 0.0f);
            float hi = fminf(hy2[bp], ty2[bt]) - fmaxf(hy1[bp], ty1[bt]);
            hi = fmaxf(hi, 0.0f);
            float inter = wi * hi;
            float uni   = ha[bp] + ta[bt] - inter;
            iou[bp][bt] = inter * frcp(uni + EPSF);
        }

    // no-obj (target 0, NO_OBJ_V3)
#pragma unroll
    for (int bp = 0; bp < 3; bp++) {
        float m = fmaxf(fmaxf(iou[bp][0], iou[bp][1]), iou[bp][2]);
        acc_noobj += (m < 0.7f) ? K.acf[bp] * K.acf[bp] : 0.0f;
    }

    // argmax over pred boxes per target (first-max ties, like jnp.argmax)
    int sel[3];
#pragma unroll
    for (int bt = 0; bt < 3; bt++) {
        int s = 0; float v = iou[0][bt];
        if (iou[1][bt] > v) { v = iou[1][bt]; s = 1; }
        if (iou[2][bt] > v) { s = 2; }
        sel[bt] = s;
    }

    float ho[3];
#pragma unroll
    for (int bt = 0; bt < 3; bt++) {
        int sp = sel[bt];
        float hoo = (K.tcf[bt] > 0.0f) ? 1.0f : 0.0f;
        ho[bt] = hoo;
        float phx = sel3(sp, K.abox[0].x, K.abox[1].x, K.abox[2].x);
        float phy = sel3(sp, K.abox[0].y, K.abox[1].y, K.abox[2].y);
        float phw = sel3(sp, K.abox[0].z, K.abox[1].z, K.abox[2].z);
        float phh = sel3(sp, K.abox[0].w, K.abox[1].w, K.abox[2].w);
        float phc = sel3(sp, K.acf[0],  K.acf[1],  K.acf[2]);
        float rwp = sel3(sp, rw0, rw1, rw2);
        float rhp = sel3(sp, rh0, rh1, rh2);
        float rwt = (bt == 0) ? rw0 : ((bt == 1) ? rw1 : rw2);
        float rht = (bt == 0) ? rh0 : ((bt == 1) ? rh1 : rh2);
        float dx  = phx - K.tbox[bt].x;
        float dy  = phy - K.tbox[bt].y;
        float dlw = flog(phw * rwp + EPSF) - flog(K.tbox[bt].z * rwt + EPSF);
        float dlh = flog(phh * rhp + EPSF) - flog(K.tbox[bt].w * rht + EPSF);
        float csum = dx * dx + dy * dy + dlw * dlw + dlh * dlh;
        acc_coord += csum * hoo * (2.0f - K.tbox[bt].z * K.tbox[bt].w);
        float dcf = phc - K.tcf[bt];
        acc_obj += dcf * dcf * hoo;
    }

    // class: select VALUES (cndmask), not addresses
#pragma unroll
    for (int bt = 0; bt < 3; bt++) {
        int sp = sel[bt];
        float s = 0.0f;
#pragma unroll
        for (int k = 0; k < 4; k++) {
            float pa = sel3(sp, K.acl4[0][k], K.acl4[1][k], K.acl4[2][k]);
            float d  = pa - K.tcl4[bt][k];
            s += d * d;
        }
        {
            float pa = sel3(sp, K.acl1[0], K.acl1[1], K.acl1[2]);
            float d  = pa - K.tcl1[bt];
            s += d * d;
        }
        acc_class += s * ho[bt];
    }
}

__global__ __launch_bounds__(64, 2) void yolo_loss_kernel(
    const float* __restrict__ yhat, const float* __restrict__ yt,
    const float* __restrict__ anchors, float* __restrict__ out, int N)
{
    const int lane = threadIdx.x;     // 0..63 (one wave per block)
    const int grp  = lane >> 4;
    const int sub  = lane & 15;

    const int n = blockIdx.x >> 5;          // image (W = 32)
    const int w = blockIdx.x & (W - 1);     // wave within image

    // anchors[scale_idx=2][b][wh] -> flat offset 12 + 2b
    const float rw0 = frcp(anchors[12]), rh0 = frcp(anchors[13]);
    const float rw1 = frcp(anchors[14]), rh1 = frcp(anchors[15]);
    const float rw2 = frcp(anchors[16]), rh2 = frcp(anchors[17]);

    float acc_coord = 0.f, acc_class = 0.f, acc_noobj = 0.f, acc_obj = 0.f;

    const size_t imgBase = (size_t)n * S2CELLS * CH;
    const int clsOff = 5 + 5 * sub;   // lane's contiguous class window

    Chunk cur, nxt;
    int cc = w;                        // chunk id held in `cur`
    {
        const float* A = yhat + imgBase + (size_t)(cc * 4 + grp) * CH;
        const float* T = yt   + imgBase + (size_t)(cc * 4 + grp) * CH;
        loadChunk(cur, A, T, clsOff);
    }
#pragma unroll 2
    for (int c2 = w + W; c2 < NCH; c2 += W) {
        const float* A = yhat + imgBase + (size_t)(c2 * 4 + grp) * CH;
        const float* T = yt   + imgBase + (size_t)(c2 * 4 + grp) * CH;
        loadChunk(nxt, A, T, clsOff);                       // prefetch c2
        computeChunk(cur, cc * 4 + grp, rw0, rh0, rw1, rh1, rw2, rh2,
                     acc_coord, acc_class, acc_noobj, acc_obj);
        cur = nxt; cc = c2;
    }
    computeChunk(cur, cc * 4 + grp, rw0, rh0, rw1, rh1, rw2, rh2,
                 acc_coord, acc_class, acc_noobj, acc_obj);

    // ---- wave-level reduction ----
    // coord/noobj/obj replicated x16 within each group -> scale by 1/16 exact.
#pragma unroll
    for (int off = 1; off < 64; off <<= 1) {
        acc_coord += __shfl_xor(acc_coord, off, 64);
        acc_class += __shfl_xor(acc_class, off, 64);
        acc_noobj += __shfl_xor(acc_noobj, off, 64);
        acc_obj   += __shfl_xor(acc_obj,   off, 64);
    }
    if (lane < 4) {
        float v = (lane == 0) ? acc_coord :
                  (lane == 1) ? acc_class :
                  (lane == 2) ? acc_noobj : acc_obj;
        if (lane != 1) v *= 0.0625f;   // un-replicate coord/noobj/obj
        atomicAdd(&out[lane * N + n], v);
    }
}

extern "C" void kernel_launch(void* const* d_in, const int* in_sizes, int n_in,
                              void* d_out, int out_size, void* d_ws, size_t ws_size,
                              hipStream_t stream) {
    const float* yhat = (const float*)d_in[0];
    const float* yv   = (const float*)d_in[1];
    const float* anc  = (const float*)d_in[2];
    float* out = (float*)d_out;

    const int N = in_sizes[0] / (S2CELLS * CH);

    hipMemsetAsync(d_out, 0, (size_t)out_size * sizeof(float), stream);

    dim3 grid(N * W);
    yolo_loss_kernel<<<grid, 64, 0, stream>>>(yhat, yv, anc, out, N);
}